// Round 2
// baseline (259.196 us; speedup 1.0000x reference)
//
#include <hip/hip_runtime.h>

// CIR Euler-Maruyama scan, B=16384 rows x S=2048 steps.
// R3: producer-consumer wave specialization.
//
// R2 post-mortem: fusing stores into the compute loop got 167->96us but
// VALUBusy FELL to 8.4% -> still latency-bound. Cause: vmcnt is a single
// in-order counter shared by loads and stores, so the s_waitcnt vmcnt(N)
// needed to consume the prefetched W chunk also drains ~64 prior store
// acks (~300cy to L2) every tile; likewise the ds_read of the previous
// tile queues behind interleaved ds_writes on in-order lgkmcnt. With one
// wave there is nothing to hide these drains.
//
// This version: 256 blocks x 128 threads.
//   wave 0 (compute): xmean + CIR chain; only ds_writes + 16 prefetch
//     loads per tile (burst-issued at tile start into the ALTERNATE
//     register buffer, so the barrier's implicit vmcnt(0) finds them
//     landed). Clean counters -> chain runs at VALU speed.
//   wave 1 (store): ds_read_b128 from the finished LDS tile + coalesced
//     256B stores. All store-ack latency lives here, off the chain.
// Double-buffered LDS tile, one __syncthreads per tile (32 barriers).
// Register double-buffer bufA/bufB with a 2x-unrolled tile loop so all
// indexing is compile-time (no scratch).
//
// Floor: compute ~64*18cy*32 = 15us; HBM 203MB @ 6.3TB/s = 32us ->
// expect ~40-55us, memory-roofline territory.

#define B_ROWS   16384
#define SEQ      2048
#define L_X      64
#define V_LAST   0.04f
#define DT_C     (1.0f / 2048.0f)
#define PROB     0.5f

#define TILE     64
#define NT       (SEQ / TILE)     // 32 tiles
#define CHT      (TILE / 4)       // 16 float4 chunks per tile per lane
#define OSTRIDE  68               // [col][row], 16B-aligned cols, conflict-free

__device__ __forceinline__ float cir_step(float v, float c, float a1, float b1) {
    // v' = c*sqrt(max(v,0)) + (a1*v + b1);  a1 = 1-kappa*DT, b1 = kappa*DT*tol_mu
    float s = __builtin_amdgcn_sqrtf(fmaxf(v, 0.0f));
    return fmaf(c, s, fmaf(a1, v, b1));
}

// Compute one 64-step tile T: burst-prefetch tile T+1 into PB, then run the
// chain on RB, blending results into o_lds[T&1] (layout [col][row]).
#define TILE_BODY(RB, PB, T)                                                  \
    {                                                                         \
        if ((T) + 1 < NT) {                                                   \
            const int nb = ((T) + 1) * CHT;                                   \
            _Pragma("unroll")                                                 \
            for (int i = 0; i < CHT; ++i) PB[i] = Wr[nb + i];                 \
        }                                                                     \
        float* cur = &o_lds[(T) & 1][0];                                      \
        _Pragma("unroll")                                                     \
        for (int i = 0; i < CHT; ++i) {                                       \
            float4 w4 = RB[i];                                                \
            const int j = 4 * i;                                              \
            v = cir_step(v, csd * w4.x, a1, b1);                              \
            cur[(j + 0) * OSTRIDE + lane] = fmaf(PROB, v, hx);                \
            v = cir_step(v, csd * w4.y, a1, b1);                              \
            cur[(j + 1) * OSTRIDE + lane] = fmaf(PROB, v, hx);                \
            v = cir_step(v, csd * w4.z, a1, b1);                              \
            cur[(j + 2) * OSTRIDE + lane] = fmaf(PROB, v, hx);                \
            v = cir_step(v, csd * w4.w, a1, b1);                              \
            cur[(j + 3) * OSTRIDE + lane] = fmaf(PROB, v, hx);                \
        }                                                                     \
    }

// Store wave: stream finished tile T from LDS to out. Per i: one aligned
// ds_read_b128 (col=lane, rows j..j+3) + 4 coalesced 256B stores.
#define STREAM_TILE(T)                                                        \
    {                                                                         \
        const float* src = &o_lds[(T) & 1][0];                                \
        const size_t ob = (size_t)row0 * SEQ + (size_t)(T) * TILE;            \
        _Pragma("unroll")                                                     \
        for (int i = 0; i < CHT; ++i) {                                       \
            const int j = 4 * i;                                              \
            float4 a4 = *reinterpret_cast<const float4*>(                     \
                src + lane * OSTRIDE + j);                                    \
            out[ob + (size_t)(j + 0) * SEQ + lane] = a4.x;                    \
            out[ob + (size_t)(j + 1) * SEQ + lane] = a4.y;                    \
            out[ob + (size_t)(j + 2) * SEQ + lane] = a4.z;                    \
            out[ob + (size_t)(j + 3) * SEQ + lane] = a4.w;                    \
        }                                                                     \
    }

__global__ __launch_bounds__(128) void cir_scan_kernel(
    const float* __restrict__ x,      // (B, 64, 1)
    const float* __restrict__ W,      // (B, S)
    const float* __restrict__ kappa_p,
    const float* __restrict__ mu_p,
    const float* __restrict__ sigma_p,
    float* __restrict__ out)          // (B, S)
{
    __shared__ __align__(16) float o_lds[2][TILE * OSTRIDE];   // 2 x 17.4 KB

    const int tid  = threadIdx.x;
    const int wid  = tid >> 6;                 // 0 = compute wave, 1 = store wave
    const int lane = tid & 63;
    const int row0 = blockIdx.x * 64;
    const int row  = row0 + lane;

    // Per-thread state for the compute wave (garbage on wave 1, unused).
    float v = V_LAST, a1 = 0.f, b1 = 0.f, csd = 0.f, hx = 0.f;
    const float4* Wr = reinterpret_cast<const float4*>(W + (size_t)row * SEQ);
    float4 bufA[CHT], bufB[CHT];

    if (wid == 0) {
        // ---- xmean over 64 samples (256B contiguous per lane) ----
        const float4* xr = reinterpret_cast<const float4*>(x + (size_t)row * L_X);
        float sum = 0.0f;
#pragma unroll
        for (int i = 0; i < L_X / 4; ++i) {
            float4 t = xr[i];
            sum += (t.x + t.y) + (t.z + t.w);
        }
        const float xmean = sum * (1.0f / 64.0f);

        const float kappa = kappa_p[0];
        const float mu    = mu_p[0];
        const float sigma = sigma_p[0];

        const float tol_mu = mu + xmean;
        const float kdt    = kappa * DT_C;
        a1  = 1.0f - kdt;
        b1  = kdt * tol_mu;
        csd = sigma * sqrtf(DT_C);
        hx  = (1.0f - PROB) * xmean;

        // prime: tile 0 -> bufA
#pragma unroll
        for (int i = 0; i < CHT; ++i) bufA[i] = Wr[i];

        TILE_BODY(bufA, bufB, 0)           // compute tile 0, prefetch tile 1
    }
    __syncthreads();

    // tiles 1..30 in pairs (odd reads bufB, even reads bufA)
    for (int h = 0; h < (NT - 2) / 2; ++h) {
        const int t = 2 * h + 1;
        if (wid == 0) { TILE_BODY(bufB, bufA, t) }
        else          { STREAM_TILE(t - 1) }
        __syncthreads();
        if (wid == 0) { TILE_BODY(bufA, bufB, t + 1) }
        else          { STREAM_TILE(t) }
        __syncthreads();
    }

    // tile 31 (reads bufB, no prefetch) || stream tile 30
    if (wid == 0) { TILE_BODY(bufB, bufA, NT - 1) }
    else          { STREAM_TILE(NT - 2) }
    __syncthreads();

    if (wid == 1) { STREAM_TILE(NT - 1) }
}

extern "C" void kernel_launch(void* const* d_in, const int* in_sizes, int n_in,
                              void* d_out, int out_size, void* d_ws, size_t ws_size,
                              hipStream_t stream) {
    const float* x     = (const float*)d_in[0];
    const float* W     = (const float*)d_in[1];
    const float* kappa = (const float*)d_in[2];
    const float* mu    = (const float*)d_in[3];
    const float* sigma = (const float*)d_in[4];
    float* out = (float*)d_out;

    dim3 grid(B_ROWS / 64);   // 256 blocks, 1 per CU
    dim3 block(128);          // wave 0 compute, wave 1 store
    hipLaunchKernelGGL(cir_scan_kernel, grid, block, 0, stream,
                       x, W, kappa, mu, sigma, out);
}